// Round 8
// baseline (227.839 us; speedup 1.0000x reference)
//
#include <hip/hip_runtime.h>

// SpikingLayer: T=64 sequential steps over [B=32, F=16384] fp32 state.
//   state = (x + state) - act
//   state = max(state + 1.0f, 0.0f) - 1.0f   // bit-exact relu(s+1)-1, NOT max(s,-1)
//   act   = state > 0 ? floor(state) : 0
// 134 MB in + 134 MB out; floor ~43 us @ 6.3 TB/s mixed (m13 copy ceiling).
//
// R2: float4, depth-2, 8 waves/CU   -> ~71 us  (latency-bound)
// R3: scalar, depth-8, 32 waves/CU  -> ~82 us  (4x vmem instrs)
// R6: float4, depth-8 + NT ld/st    -> ~60 us  (4.5 TB/s mixed)
// R7: PF=16                         -> neutral => throughput-, not latency-bound
// R8: (a) plain (non-NT) loads — keep L3 hits on restore-resident input
//     (b) 8-deep burst groups: 8 loads | 8 computes | 8 NT stores, so DRAM
//         sees 8 KB same-direction bursts per wave (fewer rw turnarounds).

#define T_STEPS 64
#define NCHAINS (32 * 16384)       // B*F = 524288 independent chains
#define NCHAINS4 (NCHAINS / 4)     // float4 groups: 131072 threads
#define GROUP 8                    // burst depth (8 x 16B = 8 KB/wave bursts)
#define NGROUPS (T_STEPS / GROUP)

typedef float vfloat4 __attribute__((ext_vector_type(4)));

__global__ __launch_bounds__(256) void spiking_kernel(
    const vfloat4* __restrict__ in, vfloat4* __restrict__ out) {
    const int i = blockIdx.x * blockDim.x + threadIdx.x;

    float s[4] = {0.f, 0.f, 0.f, 0.f};
    float a[4] = {0.f, 0.f, 0.f, 0.f};

    vfloat4 xs[2][GROUP];

    // prime group 0 (plain loads: let L3 serve restore-resident input)
    #pragma unroll
    for (int j = 0; j < GROUP; ++j)
        xs[0][j] = in[j * NCHAINS4 + i];

    #pragma unroll
    for (int g = 0; g < NGROUPS; ++g) {
        const int cur = g & 1, nxt = cur ^ 1;

        // burst-issue next group's 8 loads before touching current group
        if (g + 1 < NGROUPS) {
            #pragma unroll
            for (int j = 0; j < GROUP; ++j)
                xs[nxt][j] = in[((g + 1) * GROUP + j) * NCHAINS4 + i];
        }

        // compute 8 sequential steps into a register out-buffer
        vfloat4 av[GROUP];
        #pragma unroll
        for (int k = 0; k < GROUP; ++k) {
            vfloat4 x = xs[cur][k];
            float xe[4] = {x.x, x.y, x.z, x.w};
            #pragma unroll
            for (int e = 0; e < 4; ++e) {
                // EXACT ref op order: s = (x + s) - a; s = max(s+1,0)-1
                float sv = (xe[e] + s[e]) - a[e];
                sv = fmaxf(sv + 1.0f, 0.0f) - 1.0f;
                s[e] = sv;
                a[e] = (sv > 0.0f) ? floorf(sv) : 0.0f;
            }
            av[k] = (vfloat4){a[0], a[1], a[2], a[3]};
        }

        // burst-store the group's 8 results (NT: output has no reader)
        #pragma unroll
        for (int k = 0; k < GROUP; ++k)
            __builtin_nontemporal_store(av[k], &out[(g * GROUP + k) * NCHAINS4 + i]);
    }
}

extern "C" void kernel_launch(void* const* d_in, const int* in_sizes, int n_in,
                              void* d_out, int out_size, void* d_ws, size_t ws_size,
                              hipStream_t stream) {
    const vfloat4* in = (const vfloat4*)d_in[0];
    vfloat4* out = (vfloat4*)d_out;
    // 131072 threads / 256 = 512 blocks -> 2 blocks/CU, 8 waves/CU
    spiking_kernel<<<NCHAINS4 / 256, 256, 0, stream>>>(in, out);
}

// Round 9
// 226.834 us; speedup vs baseline: 1.0044x; 1.0044x over previous
//
#include <hip/hip_runtime.h>

// SpikingLayer: T=64 sequential steps over [B=32, F=16384] fp32 state.
//   state = (x + state) - act
//   state = max(state + 1.0f, 0.0f) - 1.0f   // bit-exact relu(s+1)-1, NOT max(s,-1)
//   act   = state > 0 ? floor(state) : 0
// 134 MB in + 134 MB out. Plain-load HBM floor: 66 MB (L3-resident half of
// input is free) + 131 MB write = 197 MB ≈ 31 us @ 6.3 TB/s.
//
// R2: float4, depth-2, 8 waves/CU    -> ~71 us  (latency-bound)
// R3: scalar, depth-8, 32 waves/CU   -> ~82 us  (4x vmem instrs)
// R6: float4, PF=8 ring, NT ld+st    -> ~60 us  (best so far)
// R7: PF=16                          -> neutral (throughput-bound, not latency)
// R8: burst groups + plain loads     -> 81 us   (VGPR=36: compiler defeated
//                                      the burst structure, MLP collapsed)
// R9: R6 structure verbatim, ONE change: plain loads (keep NT stores).
//     Tests whether L3 hits (FETCH 66 vs 134 MB HBM read) beat NT bypass.

#define T_STEPS 64
#define NCHAINS (32 * 16384)       // B*F = 524288 independent chains
#define NCHAINS4 (NCHAINS / 4)     // float4 groups: 131072 threads
#define PF 8                       // prefetch ring depth (float4 -> 8 KB/wave)

typedef float vfloat4 __attribute__((ext_vector_type(4)));

__global__ __launch_bounds__(256) void spiking_kernel(
    const vfloat4* __restrict__ in, vfloat4* __restrict__ out) {
    const int i = blockIdx.x * blockDim.x + threadIdx.x;

    float s[4] = {0.f, 0.f, 0.f, 0.f};
    float a[4] = {0.f, 0.f, 0.f, 0.f};

    vfloat4 xs[PF];
    // prime the ring: 8 KB/wave in flight before any compute
    // plain loads: let L3 serve the restore-resident half of the input
    #pragma unroll
    for (int j = 0; j < PF; ++j)
        xs[j] = in[j * NCHAINS4 + i];

    // fully unrolled: ring index + guard are compile-time static
    #pragma unroll
    for (int t = 0; t < T_STEPS; ++t) {
        vfloat4 x = xs[t % PF];
        if (t + PF < T_STEPS)
            xs[t % PF] = in[(t + PF) * NCHAINS4 + i];

        float xe[4] = {x.x, x.y, x.z, x.w};
        #pragma unroll
        for (int e = 0; e < 4; ++e) {
            // EXACT ref op order: s = (x + s) - a; s = max(s+1,0)-1; a = spikes
            float sv = (xe[e] + s[e]) - a[e];
            sv = fmaxf(sv + 1.0f, 0.0f) - 1.0f;
            s[e] = sv;
            a[e] = (sv > 0.0f) ? floorf(sv) : 0.0f;
        }

        vfloat4 av = {a[0], a[1], a[2], a[3]};
        // NT store: output has no reader; don't evict input from L3
        __builtin_nontemporal_store(av, &out[t * NCHAINS4 + i]);
    }
}

extern "C" void kernel_launch(void* const* d_in, const int* in_sizes, int n_in,
                              void* d_out, int out_size, void* d_ws, size_t ws_size,
                              hipStream_t stream) {
    const vfloat4* in = (const vfloat4*)d_in[0];
    vfloat4* out = (vfloat4*)d_out;
    // 131072 threads / 256 = 512 blocks -> 2 blocks/CU, 8 waves/CU
    spiking_kernel<<<NCHAINS4 / 256, 256, 0, stream>>>(in, out);
}

// Round 10
// 219.033 us; speedup vs baseline: 1.0402x; 1.0356x over previous
//
#include <hip/hip_runtime.h>

// SpikingLayer: T=64 sequential steps over [B=32, F=16384] fp32 state.
//   state = (x + state) - act
//   state = max(state + 1.0f, 0.0f) - 1.0f   // bit-exact relu(s+1)-1, NOT max(s,-1)
//   act   = state > 0 ? floor(state) : 0
// 134 MB in + 134 MB out; m13 copy ceiling 6.29 TB/s => ~43 us floor.
//
// R2: float4 PF2            ~74 us | R3: scalar 32w   ~83 us
// R6: float4 PF8 NT ld+st   ~70 us | R7: PF16         neutral (not latency)
// R8: reg burst-buffers      81 us (compiler collapsed, VGPR=36)
// R9: plain loads            79 us (L3-hit theory falsified; NT bypass wins)
// R10: phase-split via LDS out-buffer. Compute 16 steps -> LDS (private slot,
//   stride-1 b128, no barrier), then drain 16 NT stores back-to-back.
//   - DRAM sees long same-direction bursts (fewer rw turnarounds)
//   - store acks only block the drain loop, not the load-consume chain
//   - LDS is memory: regalloc CANNOT collapse the buffer (R8's failure mode)

#define T_STEPS 64
#define NCHAINS (32 * 16384)       // B*F = 524288 independent chains
#define NCHAINS4 (NCHAINS / 4)     // float4 groups: 131072 threads
#define PF 8                       // load prefetch ring depth
#define PHASE 16                   // t-steps buffered in LDS per phase
#define NPHASE (T_STEPS / PHASE)

typedef float vfloat4 __attribute__((ext_vector_type(4)));

__global__ __launch_bounds__(256) void spiking_kernel(
    const vfloat4* __restrict__ in, vfloat4* __restrict__ out) {
    const int i = blockIdx.x * blockDim.x + threadIdx.x;
    const int tid = threadIdx.x;

    // 16 x 256 x 16B = 64 KB/block -> 2 blocks/CU, 8 waves/CU.
    // Layout [t][thread]: lanes stride-1 -> conflict-free b128 access.
    __shared__ vfloat4 lds[PHASE][256];

    float s[4] = {0.f, 0.f, 0.f, 0.f};
    float a[4] = {0.f, 0.f, 0.f, 0.f};

    vfloat4 xs[PF];
    // prime the load ring (NT: streaming, don't allocate in cache)
    #pragma unroll
    for (int j = 0; j < PF; ++j)
        xs[j] = __builtin_nontemporal_load(&in[j * NCHAINS4 + i]);

    #pragma unroll
    for (int p = 0; p < NPHASE; ++p) {
        // ---- compute sub-phase: pure load stream, results -> LDS ----
        #pragma unroll
        for (int k = 0; k < PHASE; ++k) {
            const int t = p * PHASE + k;
            vfloat4 x = xs[t % PF];
            if (t + PF < T_STEPS)
                xs[t % PF] = __builtin_nontemporal_load(&in[(t + PF) * NCHAINS4 + i]);

            float xe[4] = {x.x, x.y, x.z, x.w};
            #pragma unroll
            for (int e = 0; e < 4; ++e) {
                // EXACT ref op order: s = (x + s) - a; s = max(s+1,0)-1
                float sv = (xe[e] + s[e]) - a[e];
                sv = fmaxf(sv + 1.0f, 0.0f) - 1.0f;
                s[e] = sv;
                a[e] = (sv > 0.0f) ? floorf(sv) : 0.0f;
            }
            lds[k][tid] = (vfloat4){a[0], a[1], a[2], a[3]};
        }

        // ---- drain sub-phase: pure store burst (own slot, no barrier) ----
        #pragma unroll
        for (int k = 0; k < PHASE; ++k) {
            vfloat4 v = lds[k][tid];
            __builtin_nontemporal_store(v, &out[(p * PHASE + k) * NCHAINS4 + i]);
        }
    }
}

extern "C" void kernel_launch(void* const* d_in, const int* in_sizes, int n_in,
                              void* d_out, int out_size, void* d_ws, size_t ws_size,
                              hipStream_t stream) {
    const vfloat4* in = (const vfloat4*)d_in[0];
    vfloat4* out = (vfloat4*)d_out;
    // 131072 threads / 256 = 512 blocks -> 2 blocks/CU, 8 waves/CU
    spiking_kernel<<<NCHAINS4 / 256, 256, 0, stream>>>(in, out);
}

// Round 11
// 217.756 us; speedup vs baseline: 1.0463x; 1.0059x over previous
//
#include <hip/hip_runtime.h>

// SpikingLayer: T=64 sequential steps over [B=32, F=16384] fp32 state.
//   state = (x + state) - act
//   state = max(state + 1.0f, 0.0f) - 1.0f   // bit-exact relu(s+1)-1, NOT max(s,-1)
//   act   = state > 0 ? floor(state) : 0
// 134 MB in + 134 MB out; m13 copy ceiling 6.29 TB/s => ~43 us floor.
//
// Falsification ledger (kernel-est):
// R2: float4 PF2 plain+plain   ~74 us | R3: scalar 32w plain+NT?  ~83 us
// R6: float4 PF8 NT+NT         ~70 us | R7: PF16 NT+NT            neutral
// R8: reg bursts (collapsed)    81 us | R9: plain-ld + NT-st       79 us
// R10: LDS phase-split NT+NT   neutral => rw-turnaround falsified
// R11: last open cell of the 2x2 policy matrix: NT loads + PLAIN stores.
//   Theory: 131 MB output write-allocates into the 256 MB memory-side
//   Infinity Cache (fits!); NT loads keep the input stream from evicting
//   it; stores complete at MALL speed, HBM bus stays read-dominated.

#define T_STEPS 64
#define NCHAINS (32 * 16384)       // B*F = 524288 independent chains
#define NCHAINS4 (NCHAINS / 4)     // float4 groups: 131072 threads
#define PF 8                       // prefetch ring depth (float4 -> 8 KB/wave)

typedef float vfloat4 __attribute__((ext_vector_type(4)));

__global__ __launch_bounds__(256) void spiking_kernel(
    const vfloat4* __restrict__ in, vfloat4* __restrict__ out) {
    const int i = blockIdx.x * blockDim.x + threadIdx.x;

    float s[4] = {0.f, 0.f, 0.f, 0.f};
    float a[4] = {0.f, 0.f, 0.f, 0.f};

    vfloat4 xs[PF];
    // prime the ring: 8 KB/wave in flight before any compute
    #pragma unroll
    for (int j = 0; j < PF; ++j)
        xs[j] = __builtin_nontemporal_load(&in[j * NCHAINS4 + i]);

    // fully unrolled: ring index + guard are compile-time static
    #pragma unroll
    for (int t = 0; t < T_STEPS; ++t) {
        vfloat4 x = xs[t % PF];
        if (t + PF < T_STEPS)
            xs[t % PF] = __builtin_nontemporal_load(&in[(t + PF) * NCHAINS4 + i]);

        float xe[4] = {x.x, x.y, x.z, x.w};
        #pragma unroll
        for (int e = 0; e < 4; ++e) {
            // EXACT ref op order: s = (x + s) - a; s = max(s+1,0)-1; a = spikes
            float sv = (xe[e] + s[e]) - a[e];
            sv = fmaxf(sv + 1.0f, 0.0f) - 1.0f;
            s[e] = sv;
            a[e] = (sv > 0.0f) ? floorf(sv) : 0.0f;
        }

        // PLAIN store: write-allocate into memory-side L3 (output fits in
        // 256 MB MALL; drains to HBM lazily, off the kernel's critical path)
        out[t * NCHAINS4 + i] = (vfloat4){a[0], a[1], a[2], a[3]};
    }
}

extern "C" void kernel_launch(void* const* d_in, const int* in_sizes, int n_in,
                              void* d_out, int out_size, void* d_ws, size_t ws_size,
                              hipStream_t stream) {
    const vfloat4* in = (const vfloat4*)d_in[0];
    vfloat4* out = (vfloat4*)d_out;
    // 131072 threads / 256 = 512 blocks -> 2 blocks/CU, 8 waves/CU
    spiking_kernel<<<NCHAINS4 / 256, 256, 0, stream>>>(in, out);
}